// Round 9
// baseline (141.502 us; speedup 1.0000x reference)
//
#include <hip/hip_runtime.h>
#include <math.h>

#define BLOCK 256
#define GOAL_MAX 1024            // LDS goal table: 12*H words (H=256 -> 12 KB)

typedef unsigned int u32;

__device__ __forceinline__ void pose_cost(const float* __restrict__ R,
                                          const float* __restrict__ P,
                                          const float* __restrict__ G,
                                          const float* __restrict__ GP,
                                          float& cost, float& rotn, float& gd)
{
  // t[i] = -sum_j G[j,i]*GP[j] + sum_j R[j,i]*P[j]
  float t0 = 0.f, t1 = 0.f, t2 = 0.f;
  #pragma unroll
  for (int j = 0; j < 3; ++j) {
    t0 += R[j*3+0]*P[j] - G[j*3+0]*GP[j];
    t1 += R[j*3+1]*P[j] - G[j*3+1]*GP[j];
    t2 += R[j*3+2]*P[j] - G[j*3+2]*GP[j];
  }
  const float pos_err = t0*t0 + t1*t1 + t2*t2;
  gd = __builtin_amdgcn_sqrtf(pos_err);                    // arg >= 0

  // ee_R_g[i,j] = sum_k G[k,i]*R[k,j]; d = I - ee_R_g
  float rn[3];
  #pragma unroll
  for (int i = 0; i < 3; ++i) {
    float q = 0.f;
    #pragma unroll
    for (int j = 0; j < 3; ++j) {
      float m = G[0+i]*R[0+j] + G[3+i]*R[3+j] + G[6+i]*R[6+j];
      float d = (i == j ? 1.f : 0.f) - m;
      q += d*d;
    }
    rn[i] = __builtin_amdgcn_sqrtf(q);
  }
  const float ssum = rn[0] + rn[1] + rn[2];
  rotn = __builtin_amdgcn_sqrtf(rn[0]*rn[0] + rn[1]*rn[1] + rn[2]*rn[2]);
  // rot_err = ssum^2 hinged on gd <= 100; sqrt(ssum^2)==ssum (ssum>=0);
  // convergence thresholds are 0 -> no-op on non-negative values.
  cost = (gd <= 100.0f ? ssum : 0.f) + gd;
}

// MLP-doubled direct streaming: each thread handles TWO poses from two
// coalesced streams (idx and idx + N/2). All 24 rot/pos loads are independent
// and issued before any use -> 2x outstanding misses per wave vs R7 (the one
// axis never isolated; R5 showed 2.9 TB/s with high per-thread MLP).
// (N/2) % H == 0 -> both poses share the SAME goal record: 3 LDS b128 reads
// serve both. No grid-stride loop, no barriers after the goal staging.
__global__ __launch_bounds__(BLOCK) void traj_cost_mlp2(
    const float* __restrict__ pos,    // (N, 3)
    const float* __restrict__ rot,    // (N, 3, 3)
    const float* __restrict__ gpos,   // (H, 3)
    const float* __restrict__ grot,   // (H, 3, 3)
    float* __restrict__ out,          // cost[N] | rot_err_norm[N] | goal_dist[N]
    long long N, int H)
{
  extern __shared__ float sg[];       // 12*H words: record h = [9 rot | 3 pos]
  const int tid = threadIdx.x;
  const u32 uH = (u32)H;

  for (u32 k = tid; k < 12u * uH; k += BLOCK) {
    const u32 r = k / 12u, c = k % 12u;
    sg[k] = (c < 9u) ? grot[r * 9u + c] : gpos[r * 3u + (c - 9u)];
  }
  __syncthreads();                    // the only barrier in the kernel

  const long long half = N >> 1;
  const long long idx = (long long)blockIdx.x * BLOCK + tid;
  if (idx >= half) return;
  const long long idx2 = idx + half;

  // ---- issue ALL 24 pose loads up front (independent, coalesced:
  //      lane word-stride 9/3 -> dense 2.3KB/0.75KB windows per wave-instr)
  float Ra[9], Pa[3], Rb[9], Pb[3];
  const float* rpa = rot + idx  * 9;
  const float* rpb = rot + idx2 * 9;
  const float* ppa = pos + idx  * 3;
  const float* ppb = pos + idx2 * 3;
  #pragma unroll
  for (int c = 0; c < 9; ++c) Ra[c] = rpa[c];
  #pragma unroll
  for (int c = 0; c < 9; ++c) Rb[c] = rpb[c];
  #pragma unroll
  for (int c = 0; c < 3; ++c) Pa[c] = ppa[c];
  #pragma unroll
  for (int c = 0; c < 3; ++c) Pb[c] = ppb[c];

  // shared goal record: h(idx) == h(idx2) because (N/2) % H == 0
  const u32 h = (u32)(idx % (long long)H);
  float G[12];
  const float4* g4 = (const float4*)(sg + (size_t)h * 12u);
  ((float4*)G)[0] = g4[0];
  ((float4*)G)[1] = g4[1];
  ((float4*)G)[2] = g4[2];

  float c0, c1, c2;
  pose_cost(Ra, Pa, G, G + 9, c0, c1, c2);
  out[idx]         = c0;
  out[N + idx]     = c1;
  out[2 * N + idx] = c2;

  pose_cost(Rb, Pb, G, G + 9, c0, c1, c2);
  out[idx2]         = c0;
  out[N + idx2]     = c1;
  out[2 * N + idx2] = c2;
}

// Generic fallback (R7 structure): one pose per thread, grid-stride.
__global__ __launch_bounds__(BLOCK) void traj_cost_direct(
    const float* __restrict__ pos, const float* __restrict__ rot,
    const float* __restrict__ gpos, const float* __restrict__ grot,
    float* __restrict__ out, long long N, int H, int hstaged)
{
  extern __shared__ float sg[];
  const int tid = threadIdx.x;
  const u32 uH = (u32)H;

  if (hstaged) {
    for (u32 k = tid; k < 12u * uH; k += BLOCK) {
      const u32 r = k / 12u, c = k % 12u;
      sg[k] = (c < 9u) ? grot[r * 9u + c] : gpos[r * 3u + (c - 9u)];
    }
    __syncthreads();
  }

  const long long stride = (long long)gridDim.x * BLOCK;
  for (long long idx = (long long)blockIdx.x * BLOCK + tid; idx < N;
       idx += stride) {
    const u32 h = (u32)(idx % (long long)H);
    float R[9], P[3], G[12];
    const float* rp = rot + idx * 9;
    const float* pp = pos + idx * 3;
    #pragma unroll
    for (int c = 0; c < 9; ++c) R[c] = rp[c];
    #pragma unroll
    for (int c = 0; c < 3; ++c) P[c] = pp[c];
    if (hstaged) {
      const float4* g4 = (const float4*)(sg + (size_t)h * 12u);
      ((float4*)G)[0] = g4[0];
      ((float4*)G)[1] = g4[1];
      ((float4*)G)[2] = g4[2];
    } else {
      #pragma unroll
      for (int c = 0; c < 9; ++c) G[c] = grot[(size_t)h * 9 + c];
      #pragma unroll
      for (int c = 0; c < 3; ++c) G[9 + c] = gpos[(size_t)h * 3 + c];
    }
    float c0, c1, c2;
    pose_cost(R, P, G, G + 9, c0, c1, c2);
    out[idx]         = c0;
    out[N + idx]     = c1;
    out[2 * N + idx] = c2;
  }
}

extern "C" void kernel_launch(void* const* d_in, const int* in_sizes, int n_in,
                              void* d_out, int out_size, void* d_ws, size_t ws_size,
                              hipStream_t stream) {
  (void)n_in; (void)out_size; (void)d_ws; (void)ws_size;

  const float* pos  = (const float*)d_in[0];
  const float* rot  = (const float*)d_in[1];
  const float* gpos = (const float*)d_in[2];
  const float* grot = (const float*)d_in[3];
  float* out = (float*)d_out;

  const long long N = (long long)in_sizes[0] / 3;   // B*H poses
  const int H = in_sizes[2] / 3;

  const int hstaged = (H <= GOAL_MAX) ? 1 : 0;
  const size_t smem = hstaged ? (size_t)12 * H * sizeof(float) : 0;

  const bool fast = hstaged && (N % 2 == 0) && ((N / 2) % H == 0) &&
                    ((N / 2) % BLOCK == 0);

  if (fast) {
    const int blocks = (int)((N / 2) / BLOCK);   // exact cover, no loop
    traj_cost_mlp2<<<blocks, BLOCK, smem, stream>>>(pos, rot, gpos, grot,
                                                    out, N, H);
  } else {
    long long nb = (N + BLOCK - 1) / BLOCK;
    const int blocks = (int)(nb < 2048 ? nb : 2048);
    traj_cost_direct<<<blocks, BLOCK, smem, stream>>>(pos, rot, gpos, grot,
                                                      out, N, H, hstaged);
  }
}